// Round 5
// baseline (1538.396 us; speedup 1.0000x reference)
//
#include <hip/hip_runtime.h>

#define B_  32
#define D_  256
#define N_  2048
#define K_  512
#define V_  6
#define DN_ (D_*N_)        // 524288
#define DK_ (D_*K_)        // 131072
#define QSZ (B_*D_*N_)     // 16777216
#define TOKSZ (B_*N_)      // 65536
#define TOK_OFF QSZ
#define LOSS_OFF (QSZ + V_*TOKSZ)
#define MARGIN 0.02f
#define FCAP 16384
#define TPB_ 32                  // tokens per block
#define NBLK (TOKSZ/TPB_)        // 2048 blocks per layer

typedef __attribute__((ext_vector_type(8))) short short8b;   // 8 bf16 (4 VGPR)
typedef __attribute__((ext_vector_type(4))) float f32x4;

__device__ __forceinline__ unsigned short f2bf(float x) {
  unsigned u = __float_as_uint(x);
  unsigned r = (u + 0x7fffu + ((u >> 16) & 1u)) >> 16;   // RNE
  return (unsigned short)r;
}
__device__ __forceinline__ float bf2f(unsigned short h) {
  return __uint_as_float(((unsigned)h) << 16);
}
__device__ __forceinline__ unsigned orderf(float f) {   // total order as unsigned
  unsigned u = __float_as_uint(f);
  return (u >> 31) ? ~u : (u | 0x80000000u);
}
__device__ __forceinline__ float unorderf(unsigned u) {
  return __uint_as_float((u & 0x80000000u) ? (u & 0x7fffffffu) : ~u);
}
__device__ __forceinline__ unsigned long long shfl_xor_u64(unsigned long long v, int m) {
  int lo = __shfl_xor((int)(unsigned)(v & 0xffffffffull), m, 64);
  int hi = __shfl_xor((int)(unsigned)(v >> 32), m, 64);
  return ((unsigned long long)(unsigned)hi << 32) | (unsigned)lo;
}

// ---- prep: transpose emb[v][d][k] -> Ef32[vk][d] + bf16 hi/lo packs ----
__global__ __launch_bounds__(256) void pack_kernel(const float* __restrict__ emb,
                                                   float* __restrict__ Ef32,
                                                   unsigned short* __restrict__ Ehi,
                                                   unsigned short* __restrict__ Elo) {
  __shared__ float T[64][68];
  const int tid = threadIdx.x;
  const int k0 = blockIdx.x * 64, d0 = blockIdx.y * 64, v = blockIdx.z;
  const float* src = emb + (size_t)v * DK_;
  const int r = tid >> 4, c4 = (tid & 15) * 4;
  #pragma unroll
  for (int i = 0; i < 4; ++i) {
    int d = d0 + r + i * 16;
    float4 x = *(const float4*)(src + (size_t)d * K_ + k0 + c4);
    *(float4*)&T[r + i * 16][c4] = x;
  }
  __syncthreads();
  #pragma unroll
  for (int i = 0; i < 4; ++i) {
    int k = k0 + r + i * 16;
    float4 wv;
    wv.x = T[c4 + 0][r + i * 16];
    wv.y = T[c4 + 1][r + i * 16];
    wv.z = T[c4 + 2][r + i * 16];
    wv.w = T[c4 + 3][r + i * 16];
    size_t o = ((size_t)v * K_ + k) * 256 + d0 + c4;
    *(float4*)(Ef32 + o) = wv;
    ushort4 hv, lv;
    hv.x = f2bf(wv.x); lv.x = f2bf(wv.x - bf2f(hv.x));
    hv.y = f2bf(wv.y); lv.y = f2bf(wv.y - bf2f(hv.y));
    hv.z = f2bf(wv.z); lv.z = f2bf(wv.z - bf2f(hv.z));
    hv.w = f2bf(wv.w); lv.w = f2bf(wv.w - bf2f(hv.w));
    *(ushort4*)(Ehi + o) = hv;
    *(ushort4*)(Elo + o) = lv;
  }
}

// ---- ||e||^2 in f32 and f64 ----
__global__ __launch_bounds__(256) void en2_kernel(const float* __restrict__ Ef32,
                                                  float* __restrict__ en2f,
                                                  double* __restrict__ en2d) {
  __shared__ double P[64][4];
  const int tid = threadIdx.x;
  const int k = blockIdx.x * 64 + (tid >> 2), q = tid & 3;
  const float* e = Ef32 + (size_t)k * 256 + q * 64;
  double s = 0.0;
  #pragma unroll 8
  for (int i = 0; i < 64; ++i) { double x = (double)e[i]; s = fma(x, x, s); }
  P[tid >> 2][q] = s;
  __syncthreads();
  if (tid < 64) {
    int k2 = blockIdx.x * 64 + tid;
    double t = (P[tid][0] + P[tid][1]) + (P[tid][2] + P[tid][3]);
    en2d[k2] = t;
    en2f[k2] = (float)t;
  }
}

// ---- inputs[b][d][n] -> Rhi/Rlo[(b*N+n)][d] (hi/lo bf16 split) ----
__global__ __launch_bounds__(256) void split_in(const float* __restrict__ in,
                                                unsigned short* __restrict__ Rhi,
                                                unsigned short* __restrict__ Rlo) {
  __shared__ float T[64][68];
  const int tid = threadIdx.x;
  const int n0 = blockIdx.x * 64, d0 = blockIdx.y * 64, b = blockIdx.z;
  const float* src = in + (size_t)b * DN_;
  const int r = tid >> 4, c4 = (tid & 15) * 4;
  #pragma unroll
  for (int i = 0; i < 4; ++i) {
    int d = d0 + r + i * 16;
    float4 v = *(const float4*)(src + (size_t)d * N_ + n0 + c4);
    *(float4*)&T[r + i * 16][c4] = v;
  }
  __syncthreads();
  #pragma unroll
  for (int i = 0; i < 4; ++i) {
    int n = n0 + r + i * 16;
    float4 w;
    w.x = T[c4 + 0][r + i * 16];
    w.y = T[c4 + 1][r + i * 16];
    w.z = T[c4 + 2][r + i * 16];
    w.w = T[c4 + 3][r + i * 16];
    ushort4 hv, lv;
    hv.x = f2bf(w.x); lv.x = f2bf(w.x - bf2f(hv.x));
    hv.y = f2bf(w.y); lv.y = f2bf(w.y - bf2f(hv.y));
    hv.z = f2bf(w.z); lv.z = f2bf(w.z - bf2f(hv.z));
    hv.w = f2bf(w.w); lv.w = f2bf(w.w - bf2f(hv.w));
    size_t o = ((size_t)b * N_ + n) * 256 + d0 + c4;
    *(ushort4*)(Rhi + o) = hv;
    *(ushort4*)(Rlo + o) = lv;
  }
}

// ---- fused VQ layer: LDS-free bf16x3 MFMA + argmin + hi/lo update + loss ----
template <bool LAST>
__global__ __launch_bounds__(256, 4) void vq_mfma(
    unsigned short* __restrict__ Rhi, unsigned short* __restrict__ Rlo,
    const unsigned short* __restrict__ Ehi, const unsigned short* __restrict__ Elo,
    const float* __restrict__ Ef32v, const float* __restrict__ en2f,
    float* __restrict__ tokOut, float* __restrict__ lossPart,
    int* __restrict__ flagCnt, int* __restrict__ flagList)
{
  __shared__ unsigned long long wmin[4][TPB_];
  __shared__ float wsec[4][TPB_];
  __shared__ int sIdx[TPB_];
  __shared__ float wred[4];

  const int tid = threadIdx.x;
  const int lane = tid & 63, w = tid >> 6;
  const int l15 = lane & 15, lg = lane >> 4;
  const int gt0 = blockIdx.x * TPB_;
  const int kb = w * 128;

  const unsigned short* ehiL = Ehi + (size_t)(kb + l15) * 256 + lg * 8;
  const unsigned short* eloL = Elo + (size_t)(kb + l15) * 256 + lg * 8;
  const unsigned short* ahiL = Rhi + (size_t)(gt0 + l15) * 256 + lg * 8;
  const unsigned short* aloL = Rlo + (size_t)(gt0 + l15) * 256 + lg * 8;

  f32x4 acc[2][8];
  #pragma unroll
  for (int tt = 0; tt < 2; ++tt)
    #pragma unroll
    for (int kt = 0; kt < 8; ++kt) acc[tt][kt] = (f32x4){0.f, 0.f, 0.f, 0.f};

  // barrier-free, LDS-free main loop: A and B fragments straight from L1/L2
  #pragma unroll
  for (int c = 0; c < 8; ++c) {
    short8b ah0 = *(const short8b*)(ahiL + c * 32);
    short8b ah1 = *(const short8b*)(ahiL + 4096 + c * 32);   // +16 tokens
    short8b al0 = *(const short8b*)(aloL + c * 32);
    short8b al1 = *(const short8b*)(aloL + 4096 + c * 32);
    #pragma unroll
    for (int kt = 0; kt < 8; ++kt) {
      short8b bh = *(const short8b*)(ehiL + (size_t)kt * 4096 + c * 32);
      short8b bl = *(const short8b*)(eloL + (size_t)kt * 4096 + c * 32);
      acc[0][kt] = __builtin_amdgcn_mfma_f32_16x16x32_bf16(ah0, bh, acc[0][kt], 0, 0, 0);
      acc[0][kt] = __builtin_amdgcn_mfma_f32_16x16x32_bf16(ah0, bl, acc[0][kt], 0, 0, 0);
      acc[0][kt] = __builtin_amdgcn_mfma_f32_16x16x32_bf16(al0, bh, acc[0][kt], 0, 0, 0);
      acc[1][kt] = __builtin_amdgcn_mfma_f32_16x16x32_bf16(ah1, bh, acc[1][kt], 0, 0, 0);
      acc[1][kt] = __builtin_amdgcn_mfma_f32_16x16x32_bf16(ah1, bl, acc[1][kt], 0, 0, 0);
      acc[1][kt] = __builtin_amdgcn_mfma_f32_16x16x32_bf16(al1, bh, acc[1][kt], 0, 0, 0);
    }
  }

  float en8[8];
  #pragma unroll
  for (int kt = 0; kt < 8; ++kt) en8[kt] = en2f[kb + kt * 16 + l15];

  // argmin + second-best per token (first-index tie-break like np.argmin)
  #pragma unroll
  for (int tt = 0; tt < 2; ++tt)
    #pragma unroll
    for (int r = 0; r < 4; ++r) {
      const int token = tt * 16 + lg * 4 + r;
      float dv0 = en8[0] - 2.f * acc[tt][0][r];
      unsigned long long p = ((unsigned long long)orderf(dv0) << 32) | (unsigned)(kb + l15);
      float s = 3.402823466e+38f;
      #pragma unroll
      for (int kt = 1; kt < 8; ++kt) {
        float dv = en8[kt] - 2.f * acc[tt][kt][r];
        unsigned long long pk = ((unsigned long long)orderf(dv) << 32) |
                                (unsigned)(kb + kt * 16 + l15);
        if (pk < p) { s = fminf(s, unorderf((unsigned)(p >> 32))); p = pk; }
        else s = fminf(s, dv);
      }
      #pragma unroll
      for (int m = 1; m <= 8; m <<= 1) {
        unsigned long long po = shfl_xor_u64(p, m);
        float so = __shfl_xor(s, m, 64);
        unsigned long long pmax = (po < p) ? p : po;
        s = fminf(fminf(s, so), unorderf((unsigned)(pmax >> 32)));
        p = (po < p) ? po : p;
      }
      if (l15 == 0) { wmin[w][token] = p; wsec[w][token] = s; }
    }
  __syncthreads();
  if (tid < TPB_) {
    unsigned long long p = wmin[0][tid]; float s = wsec[0][tid];
    #pragma unroll
    for (int w2 = 1; w2 < 4; ++w2) {
      unsigned long long po = wmin[w2][tid]; float so = wsec[w2][tid];
      unsigned long long pmax = (po < p) ? p : po;
      s = fminf(fminf(s, so), unorderf((unsigned)(pmax >> 32)));
      p = (po < p) ? po : p;
    }
    int kwin = (int)(p & 0xffffffffull);
    sIdx[tid] = kwin;
    tokOut[gt0 + tid] = (float)kwin;
    float bd = unorderf((unsigned)(p >> 32));
    if (s - bd < MARGIN) {
      int pos = atomicAdd(flagCnt, 1);
      if (pos < FCAP) flagList[pos] = gt0 + tid;
    }
  }
  __syncthreads();

  // residual update: rn = (hi+lo) - e  (f32, bit-identical to round-4 chain),
  // then re-split to hi/lo and store; fused commit-loss partial.
  const int uj = tid >> 3, q = tid & 7;        // token, 32-d group
  const int kw = sIdx[uj];
  const unsigned short* rh = Rhi + (size_t)(gt0 + uj) * 256 + q * 32;
  const unsigned short* rl = Rlo + (size_t)(gt0 + uj) * 256 + q * 32;
  const float* er = Ef32v + (size_t)kw * 256 + q * 32;
  float lacc = 0.f;
  #pragma unroll
  for (int i = 0; i < 4; ++i) {
    short8b h8 = *(const short8b*)(rh + i * 8);
    short8b l8 = *(const short8b*)(rl + i * 8);
    float4 e0 = *(const float4*)(er + i * 8);
    float4 e1 = *(const float4*)(er + i * 8 + 4);
    float ee[8] = {e0.x, e0.y, e0.z, e0.w, e1.x, e1.y, e1.z, e1.w};
    short8b nh, nl;
    #pragma unroll
    for (int j = 0; j < 8; ++j) {
      float rv = bf2f((unsigned short)h8[j]) + bf2f((unsigned short)l8[j]);
      float rn = rv - ee[j];
      unsigned short hh = f2bf(rn);
      nh[j] = (short)hh;
      nl[j] = (short)f2bf(rn - bf2f(hh));
      lacc += rn * rn;
    }
    if (!LAST) {
      *(short8b*)(const_cast<unsigned short*>(rh) + i * 8) = nh;
      *(short8b*)(const_cast<unsigned short*>(rl) + i * 8) = nl;
    }
  }
  #pragma unroll
  for (int m = 32; m >= 1; m >>= 1) lacc += __shfl_xor(lacc, m, 64);
  if (lane == 0) wred[w] = lacc;
  __syncthreads();
  if (tid == 0) lossPart[blockIdx.x] = (wred[0] + wred[1]) + (wred[2] + wred[3]);
}

// ---- exact f64 re-argmin, one flagged token per block-iteration, k-parallel ----
__global__ __launch_bounds__(256) void fixup_kernel(
    const float* __restrict__ inputs, const float* __restrict__ Ef32,
    const double* __restrict__ en2d,
    unsigned short* __restrict__ Rhi, unsigned short* __restrict__ Rlo,
    float* __restrict__ tokens, const int* __restrict__ flagList,
    const int* __restrict__ flagCnt, int v)
{
  __shared__ double rD[256];
  __shared__ double sbd[256];
  __shared__ int sbk[256];
  __shared__ int snk;
  const int tid = threadIdx.x;
  int cnt = flagCnt[0]; if (cnt > FCAP) cnt = FCAP;
  const float* Ev = Ef32 + (size_t)v * DK_;
  for (int i = blockIdx.x; i < cnt; i += gridDim.x) {
    const int gt = flagList[i];
    const int b = gt >> 11, n = gt & (N_ - 1);
    double r = (double)inputs[(size_t)b * DN_ + (size_t)tid * N_ + n];
    for (int u = 0; u < v; ++u) {
      int tu = (int)tokens[u * TOKSZ + gt];
      r -= (double)Ef32[(size_t)u * DK_ + (size_t)tu * 256 + tid];
    }
    rD[tid] = r;
    __syncthreads();
    double best = 1.0e300; int bk = 0;
    #pragma unroll
    for (int half = 0; half < 2; ++half) {
      const int k = tid + half * 256;
      const float* e0 = Ev + (size_t)k * 256;
      double s0 = 0.0, s1 = 0.0, s2 = 0.0, s3 = 0.0;
      #pragma unroll 8
      for (int dd = 0; dd < 256; dd += 4) {
        s0 = fma(rD[dd + 0], (double)e0[dd + 0], s0);
        s1 = fma(rD[dd + 1], (double)e0[dd + 1], s1);
        s2 = fma(rD[dd + 2], (double)e0[dd + 2], s2);
        s3 = fma(rD[dd + 3], (double)e0[dd + 3], s3);
      }
      double dist = en2d[v * K_ + k] - 2.0 * ((s0 + s1) + (s2 + s3));
      if (dist < best) { best = dist; bk = k; }   // k=tid before tid+256: keep lower
    }
    sbd[tid] = best; sbk[tid] = bk;
    __syncthreads();
    for (int st = 128; st >= 1; st >>= 1) {
      if (tid < st) {
        double od = sbd[tid + st]; int ok = sbk[tid + st];
        if (od < sbd[tid] || (od == sbd[tid] && ok < sbk[tid])) {
          sbd[tid] = od; sbk[tid] = ok;
        }
      }
      __syncthreads();
    }
    if (tid == 0) {
      int nk = sbk[0];
      int old = (int)tokens[v * TOKSZ + gt];
      if (nk != old) { tokens[v * TOKSZ + gt] = (float)nk; snk = nk; }
      else snk = -1;
    }
    __syncthreads();
    if (snk >= 0) {
      float x = (float)(rD[tid] - (double)Ev[(size_t)snk * 256 + tid]);
      unsigned short hh = f2bf(x);
      Rhi[(size_t)gt * 256 + tid] = hh;
      Rlo[(size_t)gt * 256 + tid] = f2bf(x - bf2f(hh));
    }
    __syncthreads();
  }
}

// ---- q_sum[b][d][n] = sum_v Ef32[v][tok_v][d] (overwrites Rhi/Rlo region) ----
__global__ __launch_bounds__(256) void finalize_q(const float* __restrict__ toks,
                                                  const float* __restrict__ Ef32,
                                                  float* __restrict__ out) {
  const int tid = threadIdx.x;
  const int gt = blockIdx.x * 64 + (tid >> 2);
  const int q = tid & 3;
  const int b = gt >> 11, n = gt & (N_ - 1);
  float4 a[16];
  int k0 = (int)toks[gt];
  const float* e0 = Ef32 + (size_t)k0 * 256 + q * 64;
  #pragma unroll
  for (int i = 0; i < 16; ++i) a[i] = ((const float4*)e0)[i];
  #pragma unroll
  for (int v = 1; v < V_; ++v) {
    int kv = (int)toks[v * TOKSZ + gt];
    const float* ev = Ef32 + (size_t)v * DK_ + (size_t)kv * 256 + q * 64;
    #pragma unroll
    for (int i = 0; i < 16; ++i) {
      float4 e = ((const float4*)ev)[i];
      a[i].x += e.x; a[i].y += e.y; a[i].z += e.z; a[i].w += e.w;
    }
  }
  float* dst = out + (size_t)b * DN_ + n;
  #pragma unroll
  for (int i = 0; i < 16; ++i) {
    int d = q * 64 + i * 4;
    dst[(size_t)(d + 0) * N_] = a[i].x;
    dst[(size_t)(d + 1) * N_] = a[i].y;
    dst[(size_t)(d + 2) * N_] = a[i].z;
    dst[(size_t)(d + 3) * N_] = a[i].w;
  }
}

__global__ __launch_bounds__(256) void loss_kernel(const float* __restrict__ part,
                                                   float* __restrict__ out) {
  __shared__ float s[256];
  const int tid = threadIdx.x;
  float a = 0.f;
  for (int i = tid; i < V_ * NBLK; i += 256) a += part[i];
  s[tid] = a;
  __syncthreads();
  for (int st = 128; st >= 1; st >>= 1) {
    if (tid < st) s[tid] += s[tid + st];
    __syncthreads();
  }
  if (tid == 0) out[LOSS_OFF] = s[0] * (1.0f / (float)QSZ);
}

extern "C" void kernel_launch(void* const* d_in, const int* in_sizes, int n_in,
                              void* d_out, int out_size, void* d_ws, size_t ws_size,
                              hipStream_t stream) {
  (void)in_sizes; (void)n_in; (void)out_size; (void)ws_size;
  const float* inputs = (const float*)d_in[0];
  const float* emb    = (const float*)d_in[1];
  float* out = (float*)d_out;
  char* ws = (char*)d_ws;

  unsigned short* Ehi = (unsigned short*)(ws + 0);          // 1572864 B
  unsigned short* Elo = (unsigned short*)(ws + 1572864);    // 1572864 B
  float*  Ef32 = (float*)(ws + 3145728);                    // 3145728 B
  float*  en2f = (float*)(ws + 6291456);                    // 12288 B
  double* en2d = (double*)(ws + 6303744);                   // 24576 B
  float*  part = (float*)(ws + 6328320);                    // 49152 B (V*NBLK)
  int*    flagCnt  = (int*)(ws + 6377472);                  // 24 B
  int*    flagList = (int*)(ws + 6377496);                  // 393216 B

  // residual lives as hi/lo bf16 inside the q_sum region of d_out (64 MB exactly)
  unsigned short* Rhi = (unsigned short*)out;               // 33554432 B
  unsigned short* Rlo = Rhi + (size_t)TOKSZ * 256;          // 33554432 B
  float* toks = out + TOK_OFF;

  hipMemsetAsync(flagCnt, 0, V_ * sizeof(int), stream);
  pack_kernel<<<dim3(8, 4, 6), 256, 0, stream>>>(emb, Ef32, Ehi, Elo);
  en2_kernel<<<48, 256, 0, stream>>>(Ef32, en2f, en2d);
  split_in<<<dim3(32, 4, 32), 256, 0, stream>>>(inputs, Rhi, Rlo);

  for (int v = 0; v < V_; ++v) {
    const unsigned short* ehi = Ehi + (size_t)v * DK_;
    const unsigned short* elo = Elo + (size_t)v * DK_;
    const float* ef = Ef32 + (size_t)v * DK_;
    if (v < V_ - 1)
      vq_mfma<false><<<NBLK, 256, 0, stream>>>(Rhi, Rlo, ehi, elo, ef, en2f + v * K_,
                                               toks + v * TOKSZ, part + v * NBLK,
                                               flagCnt + v, flagList + v * FCAP);
    else
      vq_mfma<true><<<NBLK, 256, 0, stream>>>(Rhi, Rlo, ehi, elo, ef, en2f + v * K_,
                                              toks + v * TOKSZ, part + v * NBLK,
                                              flagCnt + v, flagList + v * FCAP);
    fixup_kernel<<<512, 256, 0, stream>>>(inputs, Ef32, en2d, Rhi, Rlo, toks,
                                          flagList + v * FCAP, flagCnt + v, v);
  }
  finalize_q<<<TOKSZ / 64, 256, 0, stream>>>(toks, Ef32, out);
  loss_kernel<<<1, 256, 0, stream>>>(part, out);
}

// Round 6
// 730.448 us; speedup vs baseline: 2.1061x; 2.1061x over previous
//
#include <hip/hip_runtime.h>

#define B_  32
#define D_  256
#define N_  2048
#define K_  512
#define V_  6
#define DN_ (D_*N_)        // 524288
#define DK_ (D_*K_)        // 131072
#define QSZ (B_*D_*N_)     // 16777216
#define TOKSZ (B_*N_)      // 65536
#define TOK_OFF QSZ
#define LOSS_OFF (QSZ + V_*TOKSZ)
#define MARGIN 0.02f
#define TPB 64                   // tokens per block
#define NBLK (TOKSZ/TPB)         // 1024 blocks

typedef __attribute__((ext_vector_type(8))) short short8b;   // 8 bf16 (4 VGPR)
typedef __attribute__((ext_vector_type(4))) float f32x4;

__device__ __forceinline__ unsigned short f2bf(float x) {
  unsigned u = __float_as_uint(x);
  unsigned r = (u + 0x7fffu + ((u >> 16) & 1u)) >> 16;   // RNE
  return (unsigned short)r;
}
__device__ __forceinline__ float bf2f(unsigned short h) {
  return __uint_as_float(((unsigned)h) << 16);
}
__device__ __forceinline__ unsigned orderf(float f) {   // total order as unsigned
  unsigned u = __float_as_uint(f);
  return (u >> 31) ? ~u : (u | 0x80000000u);
}
__device__ __forceinline__ float unorderf(unsigned u) {
  return __uint_as_float((u & 0x80000000u) ? (u & 0x7fffffffu) : ~u);
}
__device__ __forceinline__ unsigned long long shfl_xor_u64(unsigned long long v, int m) {
  int lo = __shfl_xor((int)(unsigned)(v & 0xffffffffull), m, 64);
  int hi = __shfl_xor((int)(unsigned)(v >> 32), m, 64);
  return ((unsigned long long)(unsigned)hi << 32) | (unsigned)lo;
}

// ---- prep: transpose emb[v][d][k] -> Ef32[vk][d] + bf16 hi/lo packs ----
__global__ __launch_bounds__(256) void pack_kernel(const float* __restrict__ emb,
                                                   float* __restrict__ Ef32,
                                                   unsigned short* __restrict__ Ehi,
                                                   unsigned short* __restrict__ Elo) {
  __shared__ float T[64][68];
  const int tid = threadIdx.x;
  const int k0 = blockIdx.x * 64, d0 = blockIdx.y * 64, v = blockIdx.z;
  const float* src = emb + (size_t)v * DK_;
  const int r = tid >> 4, c4 = (tid & 15) * 4;
  #pragma unroll
  for (int i = 0; i < 4; ++i) {
    int d = d0 + r + i * 16;
    float4 x = *(const float4*)(src + (size_t)d * K_ + k0 + c4);
    *(float4*)&T[r + i * 16][c4] = x;
  }
  __syncthreads();
  #pragma unroll
  for (int i = 0; i < 4; ++i) {
    int k = k0 + r + i * 16;
    float4 wv;
    wv.x = T[c4 + 0][r + i * 16];
    wv.y = T[c4 + 1][r + i * 16];
    wv.z = T[c4 + 2][r + i * 16];
    wv.w = T[c4 + 3][r + i * 16];
    size_t o = ((size_t)v * K_ + k) * 256 + d0 + c4;
    *(float4*)(Ef32 + o) = wv;
    ushort4 hv, lv;
    hv.x = f2bf(wv.x); lv.x = f2bf(wv.x - bf2f(hv.x));
    hv.y = f2bf(wv.y); lv.y = f2bf(wv.y - bf2f(hv.y));
    hv.z = f2bf(wv.z); lv.z = f2bf(wv.z - bf2f(hv.z));
    hv.w = f2bf(wv.w); lv.w = f2bf(wv.w - bf2f(hv.w));
    *(ushort4*)(Ehi + o) = hv;
    *(ushort4*)(Elo + o) = lv;
  }
}

// ---- ||e||^2 in f32 and f64 ----
__global__ __launch_bounds__(256) void en2_kernel(const float* __restrict__ Ef32,
                                                  float* __restrict__ en2f,
                                                  double* __restrict__ en2d) {
  __shared__ double P[64][4];
  const int tid = threadIdx.x;
  const int k = blockIdx.x * 64 + (tid >> 2), q = tid & 3;
  const float* e = Ef32 + (size_t)k * 256 + q * 64;
  double s = 0.0;
  #pragma unroll 8
  for (int i = 0; i < 64; ++i) { double x = (double)e[i]; s = fma(x, x, s); }
  P[tid >> 2][q] = s;
  __syncthreads();
  if (tid < 64) {
    int k2 = blockIdx.x * 64 + tid;
    double t = (P[tid][0] + P[tid][1]) + (P[tid][2] + P[tid][3]);
    en2d[k2] = t;
    en2f[k2] = (float)t;
  }
}

// ---- fused all-6-layer RVQ: residual lives in LDS as hi/lo bf16 ----
__global__ __launch_bounds__(256, 2) void rvq_fused(
    const float* __restrict__ inputs,
    const unsigned short* __restrict__ Ehi, const unsigned short* __restrict__ Elo,
    const float* __restrict__ Ef32, const float* __restrict__ en2f,
    const double* __restrict__ en2d,
    float* __restrict__ tokens, float* __restrict__ lossPart)
{
  __shared__ unsigned short Ahi[8 * 2048];   // 32 KB  [c][g][tok][8]
  __shared__ unsigned short Alo[8 * 2048];   // 32 KB
  __shared__ unsigned long long wmin[4][TPB];// 2 KB
  __shared__ float wsec[4][TPB];             // 1 KB
  __shared__ int sIdx[TPB];
  __shared__ int sHist[V_][TPB];             // 1.5 KB
  __shared__ double rD[256];                 // 2 KB (fixup scratch)
  __shared__ double sbd[256];                // 2 KB
  __shared__ int sbk[256];                   // 1 KB
  __shared__ unsigned long long sFlag;
  __shared__ float wred[4];

  const int tid = threadIdx.x;
  const int lane = tid & 63, w = tid >> 6;
  const int l15 = lane & 15, lg = lane >> 4;
  const int gt0 = blockIdx.x * TPB;
  const int b = gt0 >> 11, n0 = gt0 & (N_ - 1);
  const int kb = w * 128;

  // ---- stage inputs once: coalesced reads, conflict-free b128 LDS writes
  {
    const float* src = inputs + (size_t)b * DN_ + n0 + lane;
    #pragma unroll
    for (int cc = 0; cc < 2; ++cc) {
      const int c = w * 2 + cc;
      #pragma unroll
      for (int g = 0; g < 4; ++g) {
        short8b hv, lv;
        #pragma unroll
        for (int e = 0; e < 8; ++e) {
          float x = src[(size_t)(c * 32 + g * 8 + e) * N_];
          unsigned short h = f2bf(x);
          hv[e] = (short)h;
          lv[e] = (short)f2bf(x - bf2f(h));
        }
        *(short8b*)&Ahi[c * 2048 + g * 512 + lane * 8] = hv;
        *(short8b*)&Alo[c * 2048 + g * 512 + lane * 8] = lv;
      }
    }
  }
  __syncthreads();

  for (int v = 0; v < V_; ++v) {
    const unsigned short* ehiL = Ehi + (size_t)v * DK_ + (size_t)(kb + l15) * 256 + lg * 8;
    const unsigned short* eloL = Elo + (size_t)v * DK_ + (size_t)(kb + l15) * 256 + lg * 8;
    const float* Ef32v = Ef32 + (size_t)v * DK_;

    f32x4 acc[4][8];
    #pragma unroll
    for (int tt = 0; tt < 4; ++tt)
      #pragma unroll
      for (int kt = 0; kt < 8; ++kt) acc[tt][kt] = (f32x4){0.f, 0.f, 0.f, 0.f};

    // ---- barrier-free bf16x3 MFMA over 8 d-chunks
    #pragma unroll
    for (int c = 0; c < 8; ++c) {
      short8b ah[4], al[4];
      #pragma unroll
      for (int tt = 0; tt < 4; ++tt) {
        ah[tt] = *(const short8b*)&Ahi[c * 2048 + lg * 512 + (tt * 16 + l15) * 8];
        al[tt] = *(const short8b*)&Alo[c * 2048 + lg * 512 + (tt * 16 + l15) * 8];
      }
      #pragma unroll
      for (int kt = 0; kt < 8; ++kt) {
        short8b bh = *(const short8b*)(ehiL + (size_t)kt * 4096 + c * 32);
        short8b bl = *(const short8b*)(eloL + (size_t)kt * 4096 + c * 32);
        #pragma unroll
        for (int tt = 0; tt < 4; ++tt) {
          acc[tt][kt] = __builtin_amdgcn_mfma_f32_16x16x32_bf16(ah[tt], bh, acc[tt][kt], 0, 0, 0);
          acc[tt][kt] = __builtin_amdgcn_mfma_f32_16x16x32_bf16(ah[tt], bl, acc[tt][kt], 0, 0, 0);
          acc[tt][kt] = __builtin_amdgcn_mfma_f32_16x16x32_bf16(al[tt], bh, acc[tt][kt], 0, 0, 0);
        }
      }
    }

    float en8[8];
    #pragma unroll
    for (int kt = 0; kt < 8; ++kt) en8[kt] = en2f[v * K_ + kb + kt * 16 + l15];

    // ---- argmin + second-best per token (first-index tie-break)
    #pragma unroll
    for (int tt = 0; tt < 4; ++tt)
      #pragma unroll
      for (int r = 0; r < 4; ++r) {
        const int token = tt * 16 + lg * 4 + r;
        float dv0 = en8[0] - 2.f * acc[tt][0][r];
        unsigned long long p = ((unsigned long long)orderf(dv0) << 32) | (unsigned)(kb + l15);
        float s = 3.402823466e+38f;
        #pragma unroll
        for (int kt = 1; kt < 8; ++kt) {
          float dv = en8[kt] - 2.f * acc[tt][kt][r];
          unsigned long long pk = ((unsigned long long)orderf(dv) << 32) |
                                  (unsigned)(kb + kt * 16 + l15);
          if (pk < p) { s = fminf(s, unorderf((unsigned)(p >> 32))); p = pk; }
          else s = fminf(s, dv);
        }
        #pragma unroll
        for (int m = 1; m <= 8; m <<= 1) {
          unsigned long long po = shfl_xor_u64(p, m);
          float so = __shfl_xor(s, m, 64);
          unsigned long long pmax = (po < p) ? p : po;
          s = fminf(fminf(s, so), unorderf((unsigned)(pmax >> 32)));
          p = (po < p) ? po : p;
        }
        if (l15 == 0) { wmin[w][token] = p; wsec[w][token] = s; }
      }
    __syncthreads();
    if (tid < TPB) {
      unsigned long long p = wmin[0][tid]; float s = wsec[0][tid];
      #pragma unroll
      for (int w2 = 1; w2 < 4; ++w2) {
        unsigned long long po = wmin[w2][tid]; float so = wsec[w2][tid];
        unsigned long long pmax = (po < p) ? p : po;
        s = fminf(fminf(s, so), unorderf((unsigned)(pmax >> 32)));
        p = (po < p) ? po : p;
      }
      sIdx[tid] = (int)(p & 0xffffffffull);
      float bd = unorderf((unsigned)(p >> 32));
      unsigned long long fl = __ballot(s - bd < MARGIN);
      if (tid == 0) sFlag = fl;
    }
    __syncthreads();

    // ---- in-block exact f64 re-argmin for near-tie tokens (rare)
    unsigned long long mask = sFlag;
    while (mask) {
      const int j = __builtin_ctzll(mask);
      mask &= mask - 1;
      double r = (double)inputs[(size_t)b * DN_ + (size_t)tid * N_ + (n0 + j)];
      for (int u = 0; u < v; ++u)
        r -= (double)Ef32[(size_t)u * DK_ + (size_t)sHist[u][j] * 256 + tid];
      rD[tid] = r;
      __syncthreads();
      double best = 1.0e300; int bk = 0;
      #pragma unroll
      for (int half = 0; half < 2; ++half) {
        const int k = tid + half * 256;
        const float* e0 = Ef32v + (size_t)k * 256;
        double s0 = 0.0, s1 = 0.0, s2 = 0.0, s3 = 0.0;
        #pragma unroll 8
        for (int dd = 0; dd < 256; dd += 4) {
          s0 = fma(rD[dd + 0], (double)e0[dd + 0], s0);
          s1 = fma(rD[dd + 1], (double)e0[dd + 1], s1);
          s2 = fma(rD[dd + 2], (double)e0[dd + 2], s2);
          s3 = fma(rD[dd + 3], (double)e0[dd + 3], s3);
        }
        double dist = en2d[v * K_ + k] - 2.0 * ((s0 + s1) + (s2 + s3));
        if (dist < best) { best = dist; bk = k; }   // k=tid before tid+256: keep lower
      }
      sbd[tid] = best; sbk[tid] = bk;
      __syncthreads();
      for (int st = 128; st >= 1; st >>= 1) {
        if (tid < st) {
          double od = sbd[tid + st]; int ok = sbk[tid + st];
          if (od < sbd[tid] || (od == sbd[tid] && ok < sbk[tid])) {
            sbd[tid] = od; sbk[tid] = ok;
          }
        }
        __syncthreads();
      }
      if (tid == 0) sIdx[j] = sbk[0];
      __syncthreads();
    }

    if (tid < TPB) {
      sHist[v][tid] = sIdx[tid];
      tokens[(size_t)v * TOKSZ + gt0 + tid] = (float)sIdx[tid];
    }
    __syncthreads();

    // ---- residual update in LDS: rn = (hi+lo) - e, re-split; fused loss
    const int uj = tid >> 2, q = tid & 3;
    const int kw = sIdx[uj];
    const float* er = Ef32v + (size_t)kw * 256 + q * 64;
    float lacc = 0.f;
    #pragma unroll
    for (int i = 0; i < 8; ++i) {
      const int c = q * 2 + (i >> 2), g = i & 3;
      unsigned short* ph = &Ahi[c * 2048 + g * 512 + uj * 8];
      unsigned short* pl = &Alo[c * 2048 + g * 512 + uj * 8];
      short8b h8 = *(const short8b*)ph;
      short8b l8 = *(const short8b*)pl;
      float4 e0 = *(const float4*)(er + i * 8);
      float4 e1 = *(const float4*)(er + i * 8 + 4);
      float ee[8] = {e0.x, e0.y, e0.z, e0.w, e1.x, e1.y, e1.z, e1.w};
      short8b nh, nl;
      #pragma unroll
      for (int jj = 0; jj < 8; ++jj) {
        float rv = bf2f((unsigned short)h8[jj]) + bf2f((unsigned short)l8[jj]);
        float rn = rv - ee[jj];
        unsigned short hh = f2bf(rn);
        nh[jj] = (short)hh;
        nl[jj] = (short)f2bf(rn - bf2f(hh));
        lacc += rn * rn;
      }
      if (v < V_ - 1) {
        *(short8b*)ph = nh;
        *(short8b*)pl = nl;
      }
    }
    #pragma unroll
    for (int m = 32; m >= 1; m >>= 1) lacc += __shfl_xor(lacc, m, 64);
    if (lane == 0) wred[w] = lacc;
    __syncthreads();
    if (tid == 0)
      lossPart[(size_t)v * NBLK + blockIdx.x] = (wred[0] + wred[1]) + (wred[2] + wred[3]);
    __syncthreads();   // Ahi/Alo stable + wred reusable before next layer
  }
}

// ---- q_sum[b][d][n] = sum_v Ef32[v][tok_v][d] ----
__global__ __launch_bounds__(256) void finalize_q(const float* __restrict__ toks,
                                                  const float* __restrict__ Ef32,
                                                  float* __restrict__ out) {
  const int tid = threadIdx.x;
  const int gt = blockIdx.x * 64 + (tid >> 2);
  const int q = tid & 3;
  const int b = gt >> 11, n = gt & (N_ - 1);
  float4 a[16];
  int k0 = (int)toks[gt];
  const float* e0 = Ef32 + (size_t)k0 * 256 + q * 64;
  #pragma unroll
  for (int i = 0; i < 16; ++i) a[i] = ((const float4*)e0)[i];
  #pragma unroll
  for (int v = 1; v < V_; ++v) {
    int kv = (int)toks[v * TOKSZ + gt];
    const float* ev = Ef32 + (size_t)v * DK_ + (size_t)kv * 256 + q * 64;
    #pragma unroll
    for (int i = 0; i < 16; ++i) {
      float4 e = ((const float4*)ev)[i];
      a[i].x += e.x; a[i].y += e.y; a[i].z += e.z; a[i].w += e.w;
    }
  }
  float* dst = out + (size_t)b * DN_ + n;
  #pragma unroll
  for (int i = 0; i < 16; ++i) {
    int d = q * 64 + i * 4;
    dst[(size_t)(d + 0) * N_] = a[i].x;
    dst[(size_t)(d + 1) * N_] = a[i].y;
    dst[(size_t)(d + 2) * N_] = a[i].z;
    dst[(size_t)(d + 3) * N_] = a[i].w;
  }
}

__global__ __launch_bounds__(256) void loss_kernel(const float* __restrict__ part,
                                                   float* __restrict__ out) {
  __shared__ float s[256];
  const int tid = threadIdx.x;
  float a = 0.f;
  for (int i = tid; i < V_ * NBLK; i += 256) a += part[i];
  s[tid] = a;
  __syncthreads();
  for (int st = 128; st >= 1; st >>= 1) {
    if (tid < st) s[tid] += s[tid + st];
    __syncthreads();
  }
  if (tid == 0) out[LOSS_OFF] = s[0] * (1.0f / (float)QSZ);
}

extern "C" void kernel_launch(void* const* d_in, const int* in_sizes, int n_in,
                              void* d_out, int out_size, void* d_ws, size_t ws_size,
                              hipStream_t stream) {
  (void)in_sizes; (void)n_in; (void)out_size; (void)ws_size;
  const float* inputs = (const float*)d_in[0];
  const float* emb    = (const float*)d_in[1];
  float* out = (float*)d_out;
  char* ws = (char*)d_ws;

  unsigned short* Ehi = (unsigned short*)(ws + 0);          // 1572864 B
  unsigned short* Elo = (unsigned short*)(ws + 1572864);    // 1572864 B
  float*  Ef32 = (float*)(ws + 3145728);                    // 3145728 B
  float*  en2f = (float*)(ws + 6291456);                    // 12288 B
  double* en2d = (double*)(ws + 6303744);                   // 24576 B
  float*  part = (float*)(ws + 6328320);                    // 24576 B (V*NBLK)

  float* toks = out + TOK_OFF;

  pack_kernel<<<dim3(8, 4, 6), 256, 0, stream>>>(emb, Ef32, Ehi, Elo);
  en2_kernel<<<48, 256, 0, stream>>>(Ef32, en2f, en2d);
  rvq_fused<<<NBLK, 256, 0, stream>>>(inputs, Ehi, Elo, Ef32, en2f, en2d, toks, part);
  finalize_q<<<TOKSZ / 64, 256, 0, stream>>>(toks, Ef32, out);
  loss_kernel<<<1, 256, 0, stream>>>(part, out);
}